// Round 8
// baseline (1921.219 us; speedup 1.0000x reference)
//
#include <hip/hip_runtime.h>
#include <hip/hip_bf16.h>
#include <math.h>

#define NPRED 65536
#define NGT   128
#define NCLS  256
#define CAP   12288
#define VCAP  160
#define NLIST 129    // per-row sorted prefix: 128 (max |V|) + 1 guarantees a fresh head
#define LSTRIDE 132
#define KEEP  2048
#define KMIN  1418
#define SENT_I 0x7FFFFFFF

// ---------- numeric helpers (match reference op order; no FMA contraction) ----------

__device__ __forceinline__ float sigmoid_f32(float x) {
#pragma clang fp contract(off)
    double s = 1.0 / (1.0 + exp(-(double)x));
    return (float)s;
}

// monotone map f32 -> uint32 (order-preserving for all floats)
__device__ __forceinline__ unsigned f2u(float f) {
    unsigned u = __float_as_uint(f);
    return (u & 0x80000000u) ? ~u : (u | 0x80000000u);
}
__device__ __forceinline__ float u2f(unsigned x) {
    unsigned u = (x & 0x80000000u) ? (x ^ 0x80000000u) : ~x;
    return __uint_as_float(u);
}

__device__ __forceinline__ float giou3d(
    float pl0, float pl1, float pl2, float ph0, float ph1, float ph2, float pvol,
    float gl0, float gl1, float gl2, float gh0, float gh1, float gh2, float gvol)
{
#pragma clang fp contract(off)
    float c0 = fmaxf(fminf(ph0, gh0) - fmaxf(pl0, gl0), 0.0f);
    float c1 = fmaxf(fminf(ph1, gh1) - fmaxf(pl1, gl1), 0.0f);
    float c2 = fmaxf(fminf(ph2, gh2) - fmaxf(pl2, gl2), 0.0f);
    float overlap = (c0 * c1) * c2;
    float uni = fmaxf((pvol + gvol) - overlap, 1e-6f);
    float iou = overlap / uni;
    float e0 = fmaxf(fmaxf(ph0, gh0) - fminf(pl0, gl0), 0.0f);
    float e1 = fmaxf(fmaxf(ph1, gh1) - fminf(pl1, gl1), 0.0f);
    float e2 = fmaxf(fmaxf(ph2, gh2) - fminf(pl2, gl2), 0.0f);
    float enc = fmaxf((e0 * e1) * e2, 1e-6f);
    return iou - (enc - uni) / enc;
}

// ---------- kernels ----------

__global__ void k_init(int* ccnt, unsigned* cmax, int* failFlag) {
    int t = threadIdx.x;
    if (t < NGT) { ccnt[t] = 0; cmax[t] = 0u; }
    if (t == 0) *failFlag = 0;
}

// coalesced cls load + LDS transpose + sigmoid: costT[g][p] = -sigmoid(cls[p][lab[g]])
// 1024 blocks x 256 threads; block handles 64 preds x all 256 classes.
__global__ __launch_bounds__(256) void k_gather(
    const float* __restrict__ cls, const int* __restrict__ lab,
    float* __restrict__ costT)
{
#pragma clang fp contract(off)
    __shared__ float tile[64][NCLS + 1];   // stride 257: (lane+lab)%32 -> 2-way, free
    __shared__ int labl[NGT];
    int tid = threadIdx.x;
    int p0 = blockIdx.x * 64;
    if (tid < NGT) labl[tid] = lab[tid];
    // coalesced float4 tile load: wave w loads row it*4+w (1KB contiguous per wave)
    for (int it = 0; it < 16; ++it) {
        int row = it * 4 + (tid >> 6);
        int col = (tid & 63) * 4;
        const float4 v = *(const float4*)&cls[(size_t)(p0 + row) * NCLS + col];
        tile[row][col + 0] = v.x; tile[row][col + 1] = v.y;
        tile[row][col + 2] = v.z; tile[row][col + 3] = v.w;
    }
    __syncthreads();
    int lane = tid & 63;
    for (int rep = 0; rep < 32; ++rep) {
        int g = rep * 4 + (tid >> 6);
        float val = tile[lane][labl[g]];
        double s = 1.0 / (1.0 + exp(-(double)val));
        costT[(size_t)g * NPRED + p0 + lane] = -(float)s;
    }
}

// adds the giou term on top of the staged -sigmoid: costT[g][p] += 2*(-gio)
// (bit-identical to (-sg) + (2.0f*(-gio))); also cmax + candidate collection.
__global__ __launch_bounds__(256) void k_cost(
    const float* __restrict__ pc, const float* __restrict__ ps,
    const float* __restrict__ gc, const float* __restrict__ gs,
    float* __restrict__ costT, int* __restrict__ ccnt, unsigned* __restrict__ cmax,
    int2* __restrict__ cpair)
{
#pragma clang fp contract(off)
    __shared__ float gb[NGT][6];
    __shared__ float gvol[NGT];
    int tid = threadIdx.x;
    int lane = tid & 63;
    if (tid < NGT) {
        float c0 = gc[tid * 3 + 0], c1 = gc[tid * 3 + 1], c2 = gc[tid * 3 + 2];
        float s0 = gs[tid * 3 + 0], s1 = gs[tid * 3 + 1], s2 = gs[tid * 3 + 2];
        float l0 = c0 - s0 / 2.0f, l1 = c1 - s1 / 2.0f, l2 = c2 - s2 / 2.0f;
        float h0 = c0 + s0 / 2.0f, h1 = c1 + s1 / 2.0f, h2 = c2 + s2 / 2.0f;
        gb[tid][0] = l0; gb[tid][1] = l1; gb[tid][2] = l2;
        gb[tid][3] = h0; gb[tid][4] = h1; gb[tid][5] = h2;
        gvol[tid] = ((h0 - l0) * (h1 - l1)) * (h2 - l2);
    }
    __syncthreads();

    int p = blockIdx.x * 256 + tid;
    float c0 = pc[p * 3 + 0], c1 = pc[p * 3 + 1], c2 = pc[p * 3 + 2];
    float s0 = ps[p * 3 + 0], s1 = ps[p * 3 + 1], s2 = ps[p * 3 + 2];
    float pl0 = c0 - s0 / 2.0f, pl1 = c1 - s1 / 2.0f, pl2 = c2 - s2 / 2.0f;
    float ph0 = c0 + s0 / 2.0f, ph1 = c1 + s1 / 2.0f, ph2 = c2 + s2 / 2.0f;
    float pvol = ((ph0 - pl0) * (ph1 - pl1)) * (ph2 - pl2);

    for (int g = 0; g < NGT; ++g) {
        float gio = giou3d(pl0, pl1, pl2, ph0, ph1, ph2, pvol,
                           gb[g][0], gb[g][1], gb[g][2], gb[g][3], gb[g][4], gb[g][5], gvol[g]);
        float m = gio;
        for (int off = 32; off; off >>= 1) m = fmaxf(m, __shfl_xor(m, off, 64));
        if (lane == 0) atomicMax(&cmax[g], f2u(m));
        size_t ij = (size_t)g * NPRED + p;
        float ns = costT[ij];                 // staged -sigmoid
        costT[ij] = ns + (2.0f * (-gio));     // == (-sg) + (2.0f*(-gio))
        // wave-aggregated candidate append: 1 atomic per wave per gt
        bool cand = (gio > 0.25f);
        unsigned long long mask = __ballot(cand);
        int cnt = __popcll(mask);
        int base = 0;
        if (lane == 0 && cnt) base = atomicAdd(&ccnt[g], cnt);
        base = __shfl(base, 0, 64);
        if (cand) {
            int slot = base + __popcll(mask & ((1ull << lane) - 1ull));
            if (slot < CAP) cpair[(size_t)g * CAP + slot] = make_int2(p, __float_as_int(gio));
        }
    }
}

__global__ __launch_bounds__(128) void k_sort(const unsigned* __restrict__ cmax,
                                              int* __restrict__ order) {
    __shared__ unsigned m[NGT];
    int t = threadIdx.x;
    m[t] = cmax[t];
    __syncthreads();
    unsigned mt = m[t];
    int r = 0;
    for (int k = 0; k < NGT; ++k) {
        unsigned mk = m[k];
        if (mk < mt || (mk == mt && k < t)) r++;
    }
    order[r] = t;
}

// per-row exact top-NLIST smallest (value, col) via 8-pass u64 radix-select
// (keys are unique: low 32 bits = col). 128 blocks x 256 threads.
__global__ __launch_bounds__(256) void k_toprow(
    const float* __restrict__ costT, int2* __restrict__ rowlist)
{
    __shared__ int hist[256];
    __shared__ unsigned long long keys[256];
    __shared__ unsigned long long sh_prefix;
    __shared__ int sh_rank, sh_cnt;
    int tid = threadIdx.x;
    int row = blockIdx.x;
    const float* crow = costT + (size_t)row * NPRED;
    if (tid == 0) { sh_prefix = 0ull; sh_rank = NLIST - 1; sh_cnt = 0; }
    __syncthreads();
    for (int d = 7; d >= 0; --d) {
        hist[tid] = 0;
        __syncthreads();
        unsigned long long pref = sh_prefix;
        int sh = (d + 1) * 8;
        for (int j = tid; j < NPRED; j += 256) {
            unsigned long long key = ((unsigned long long)f2u(crow[j]) << 32) | (unsigned)j;
            bool match = (sh >= 64) || ((key >> sh) == (pref >> sh));
            if (match) atomicAdd(&hist[(int)((key >> (d * 8)) & 255ull)], 1);
        }
        __syncthreads();
        if (tid == 0) {
            int rank = sh_rank, cum = 0, b = 0;
            for (; b < 256; ++b) { if (cum + hist[b] > rank) break; cum += hist[b]; }
            sh_prefix = pref | ((unsigned long long)b << (d * 8));
            sh_rank = rank - cum;
        }
        __syncthreads();
    }
    unsigned long long thr = sh_prefix;  // exact NLIST-th smallest key
    for (int j = tid; j < NPRED; j += 256) {
        unsigned long long key = ((unsigned long long)f2u(crow[j]) << 32) | (unsigned)j;
        if (key <= thr) { int s = atomicAdd(&sh_cnt, 1); keys[s] = key; }
    }
    __syncthreads();
    if (tid >= sh_cnt) keys[tid] = ~0ull;
    __syncthreads();
    for (int k = 2; k <= 256; k <<= 1) {
        for (int j2 = k >> 1; j2 > 0; j2 >>= 1) {
            int i = tid, ixj = i ^ j2;
            if (ixj > i) {
                unsigned long long a = keys[i], b2 = keys[ixj];
                bool up = ((i & k) == 0);
                if ((up && a > b2) || (!up && a < b2)) { keys[i] = b2; keys[ixj] = a; }
            }
            __syncthreads();
        }
    }
    if (tid < NLIST) {
        unsigned long long key = keys[tid];
        rowlist[row * LSTRIDE + tid] =
            make_int2(__float_as_int(u2f((unsigned)(key >> 32))),
                      (int)(unsigned)(key & 0xFFFFFFFFull));
    }
}

// sparse JV LSA, single wave. Fresh-column heads come from per-row sorted
// top-NLIST lists (first entry not in V == exact argmin over fresh columns).
// Bit-identical to dense numpy JV (exact f64 op order, (v,col,SRpos) lex ties).
__global__ __launch_bounds__(64) void k_lsa_sparse(
    const float* __restrict__ costT, const int2* __restrict__ rowlist,
    int* __restrict__ failFlag,
    unsigned* __restrict__ usedbits, int* __restrict__ out)
{
#pragma clang fp contract(off)
    __shared__ double u_l[NGT];
    __shared__ int    c4r[NGT];
    __shared__ int    slot4row[NGT];
    __shared__ int    headpos[NGT];
    __shared__ int    colidV[VCAP];
    __shared__ double vV[VCAP], shortV[VCAP];
    __shared__ int    pathV[VCAP], r4cV[VCAP];
    __shared__ unsigned char SCV[VCAP];
    __shared__ int    SRr[VCAP];
    __shared__ double headv[VCAP];
    __shared__ int    headj[VCAP];
    __shared__ unsigned vbits[2048];
    __shared__ int S_bi, S_sink, S_nSR, S_nV, S_fail, S_pendrow, S_pendpos;
    __shared__ double S_mv, S_pendmv;

    int lane = threadIdx.x;
    for (int w = lane; w < 2048; w += 64) vbits[w] = 0u;
    for (int r = lane; r < NGT; r += 64) {
        u_l[r] = 0.0; c4r[r] = -1; slot4row[r] = -1; headpos[r] = 0;
    }
    if (lane == 0) { S_nV = 0; S_fail = 0; }
    __syncthreads();

    for (int cur = 0; cur < NGT; ++cur) {
        int nV0 = S_nV;
        for (int k = lane; k < nV0; k += 64) { shortV[k] = INFINITY; pathV[k] = -1; SCV[k] = 0; }
        if (lane == 0) {
            S_bi = cur; S_sink = -1; S_mv = 0.0;
            SRr[0] = cur; S_nSR = 1;
            S_pendrow = cur; S_pendpos = 0; S_pendmv = 0.0;
        }
        __syncthreads();

        while (true) {
            // resolve pending head (whole-wave list walk, coalesced 512B loads)
            int prow = S_pendrow;
            if (prow >= 0) {
                int pos = headpos[prow];
                float hval = 0.0f; int hcol = SENT_I;
                while (pos < NLIST) {
                    int i = pos + lane;
                    int2 e = (i < NLIST) ? rowlist[prow * LSTRIDE + i] : make_int2(0, SENT_I);
                    int c = e.y;
                    bool fresh = (i < NLIST) && !((vbits[c >> 5] >> (c & 31)) & 1u);
                    unsigned long long m = __ballot(fresh);
                    if (m) {
                        int fl = __ffsll(m) - 1;
                        hcol = __shfl(c, fl, 64);
                        hval = __shfl(__int_as_float(e.x), fl, 64);
                        pos += fl;
                        break;
                    }
                    pos += 64;
                }
                if (lane == 0) {
                    headpos[prow] = pos;  // entries before pos are in V forever
                    int pp = S_pendpos;
                    headj[pp] = hcol;
                    headv[pp] = (hcol == SENT_I) ? (double)INFINITY
                                                 : ((S_pendmv + (double)hval) - u_l[prow]);
                    S_pendrow = -1;
                }
                __syncthreads();
            }

            int bi = S_bi; double mv = S_mv; int nV = S_nV; int s = S_nSR;
            double ui = u_l[bi];
            double bv = (double)INFINITY; int bj = SENT_I, bp = SENT_I, baux = -1, bisv = 0;
            // exact scan of V-members for the current row
            for (int k = lane; k < nV; k += 64) {
                if (!SCV[k]) {
                    double c = (double)costT[(size_t)bi * NPRED + colidV[k]];
                    double r = ((mv + c) - ui) - vV[k];
                    if (r < shortV[k]) { shortV[k] = r; pathV[k] = bi; }
                    double sval = shortV[k]; int scol = colidV[k];
                    if (sval < bv || (sval == bv && scol < bj)) {
                        bv = sval; bj = scol; bp = SENT_I; baux = k; bisv = 1;
                    }
                }
            }
            // per-SR-row heads (fresh columns), key (value, column, SR-position)
            for (int p = lane; p < s; p += 64) {
                double hv = headv[p]; int hj = headj[p];
                if (hv < bv || (hv == bv && (hj < bj || (hj == bj && p < bp)))) {
                    bv = hv; bj = hj; bp = p; baux = p; bisv = 0;
                }
            }
            for (int off = 1; off < 64; off <<= 1) {
                double ov = __shfl_xor(bv, off, 64);
                int oj = __shfl_xor(bj, off, 64);
                int op = __shfl_xor(bp, off, 64);
                int oa = __shfl_xor(baux, off, 64);
                int oi = __shfl_xor(bisv, off, 64);
                if (ov < bv || (ov == bv && (oj < bj || (oj == bj && op < bp)))) {
                    bv = ov; bj = oj; bp = op; baux = oa; bisv = oi;
                }
            }
            if (lane == 0) {
                S_mv = bv;
                if (bisv) {
                    SCV[baux] = 1;
                    int nr = r4cV[baux];
                    SRr[s] = nr;
                    headv[s] = (double)INFINITY; headj[s] = SENT_I;  // filled next iter
                    S_pendrow = nr; S_pendpos = s; S_pendmv = bv;
                    S_nSR = s + 1; S_bi = nr;
                } else {
                    int k2 = S_nV;
                    if (k2 >= VCAP) S_fail = 1;
                    else {
                        colidV[k2] = bj; vV[k2] = 0.0; shortV[k2] = bv;
                        pathV[k2] = SRr[baux]; SCV[k2] = 1; r4cV[k2] = -1;
                        vbits[bj >> 5] |= (1u << (bj & 31));
                        S_nV = k2 + 1;
                        S_sink = bj;
                    }
                }
            }
            __syncthreads();
            if (S_sink >= 0 || S_fail) break;
        }
        if (S_fail) break;

        double mvf = S_mv;
        int nVn = S_nV;
        for (int k = lane; k < nVn; k += 64)
            if (SCV[k]) vV[k] -= (mvf - shortV[k]);
        if (lane == 0) {
            u_l[cur] += mvf;
            int s = S_nSR;
            for (int q = 1; q < s; ++q) {
                int i2 = SRr[q];
                u_l[i2] += mvf - shortV[slot4row[i2]];
            }
            int jslot = S_nV - 1;  // sink's V slot
            while (true) {
                int i2 = pathV[jslot];
                r4cV[jslot] = i2;
                int oldslot = (c4r[i2] >= 0) ? slot4row[i2] : -1;
                c4r[i2] = colidV[jslot];
                slot4row[i2] = jslot;
                if (i2 == cur) break;
                jslot = oldslot;
            }
        }
        __syncthreads();
    }

    if (lane == 0 && S_fail) *failFlag = 1;
    __syncthreads();
    if (!S_fail) {
        for (int w = lane; w < 2048; w += 64) usedbits[w] = 0u;
        __syncthreads();
        for (int r = lane; r < NGT; r += 64) {
            int p = c4r[r];
            atomicOr(&usedbits[p >> 5], 1u << (p & 31));
            out[r] = p;
            out[1408 + r] = r;
        }
    }
}

// dense fallback: only runs if k_lsa_sparse flagged overflow (should never happen)
__global__ __launch_bounds__(1024) void k_lsa_dense(
    const float* __restrict__ costT, const int* __restrict__ failFlag,
    double* __restrict__ v, double* __restrict__ shortest,
    int* __restrict__ path, int* __restrict__ row4col,
    unsigned char* __restrict__ SC, unsigned* __restrict__ usedbits,
    int* __restrict__ out)
{
#pragma clang fp contract(off)
    if (*failFlag == 0) return;
    __shared__ double u_l[NGT];
    __shared__ int    c4r[NGT];
    __shared__ int    SR[NGT + 1];
    __shared__ int    bi, bsink, nSR;
    __shared__ double bmin;
    __shared__ double wval[16];
    __shared__ int    widx[16];
    int tid = threadIdx.x;

    for (int j = tid; j < NPRED; j += 1024) { v[j] = 0.0; row4col[j] = -1; }
    if (tid < NGT) { u_l[tid] = 0.0; c4r[tid] = -1; }
    __syncthreads();

    for (int cur = 0; cur < NGT; ++cur) {
        for (int j = tid; j < NPRED; j += 1024) {
            shortest[j] = (double)INFINITY; path[j] = -1; SC[j] = 0;
        }
        if (tid == 0) { bi = cur; bsink = -1; bmin = 0.0; SR[0] = cur; nSR = 1; }
        __syncthreads();

        while (true) {
            int irow = bi;
            double mv = bmin;
            double ui = u_l[irow];
            const float* crow = costT + (size_t)irow * NPRED;
            double bestv = (double)INFINITY;
            int    bestj = SENT_I;
            for (int j = tid; j < NPRED; j += 1024) {
                if (!SC[j]) {
                    double s = shortest[j];
                    double r = ((mv + (double)crow[j]) - ui) - v[j];
                    if (r < s) { s = r; shortest[j] = r; path[j] = irow; }
                    if (s < bestv || (s == bestv && j < bestj)) { bestv = s; bestj = j; }
                }
            }
            for (int off = 32; off; off >>= 1) {
                double ov = __shfl_down(bestv, off, 64);
                int    oj = __shfl_down(bestj, off, 64);
                if (ov < bestv || (ov == bestv && oj < bestj)) { bestv = ov; bestj = oj; }
            }
            if ((tid & 63) == 0) { wval[tid >> 6] = bestv; widx[tid >> 6] = bestj; }
            __syncthreads();
            if (tid == 0) {
                double bv = wval[0]; int bj = widx[0];
                for (int w = 1; w < 16; ++w) {
                    double ov = wval[w]; int oj = widx[w];
                    if (ov < bv || (ov == bv && oj < bj)) { bv = ov; bj = oj; }
                }
                bmin = bv;
                SC[bj] = 1;
                int r = row4col[bj];
                if (r < 0) { bsink = bj; }
                else       { SR[nSR++] = r; bi = r; }
            }
            __syncthreads();
            if (bsink >= 0) break;
        }

        double mv = bmin;
        for (int j = tid; j < NPRED; j += 1024)
            if (SC[j]) v[j] -= (mv - shortest[j]);
        if (tid == 0) {
            u_l[cur] += mv;
            for (int k = 1; k < nSR; ++k) {
                int i2 = SR[k];
                u_l[i2] += mv - shortest[c4r[i2]];
            }
            int j = bsink;
            while (true) {
                int i2 = path[j];
                row4col[j] = i2;
                int nj = c4r[i2];
                c4r[i2] = j;
                j = nj;
                if (i2 == cur) break;
            }
        }
        __syncthreads();
    }

    for (int w = tid; w < 2048; w += 1024) usedbits[w] = 0u;
    __syncthreads();
    for (int j = tid; j < NPRED; j += 1024)
        if (row4col[j] >= 0) atomicOr(&usedbits[j >> 5], 1u << (j & 31));
    if (tid < NGT) {
        out[tid]        = c4r[tid];
        out[1408 + tid] = tid;
    }
}

// per-gt: histogram-select top >=KMIN by (val desc, idx asc), compact <=KEEP-1,
// bitonic-sort KEEP u64 keys in LDS, write sorted prefix. 128 blocks x 256 thr.
__global__ __launch_bounds__(256) void k_prep(
    const int2* __restrict__ cpair, const int* __restrict__ ccnt,
    unsigned long long* __restrict__ scand, int* __restrict__ kcount,
    int* __restrict__ fullflag)
{
    __shared__ int hist[256];
    __shared__ unsigned long long keys[KEEP];
    __shared__ unsigned sh_pref, sh_thresh;
    __shared__ int sh_done, sh_fail, sh_cnt;
    int tid = threadIdx.x;
    int g = blockIdx.x;
    int nc = ccnt[g]; if (nc > CAP) nc = CAP;
    const int2* src = cpair + (size_t)g * CAP;

    unsigned thresh = 0;
    if (nc > KEEP - 1) {
        if (tid == 0) { sh_pref = 0; sh_done = 0; sh_fail = 0; }
        __syncthreads();
        int above = 0;  // live only on tid 0
        for (int byt = 3; byt >= 0; --byt) {
            hist[tid] = 0;
            __syncthreads();
            unsigned pref = sh_pref;
            for (int c = tid; c < nc; c += 256) {
                unsigned u = f2u(__int_as_float(src[c].y));
                if (byt == 3 || (u >> ((byt + 1) * 8)) == (pref >> ((byt + 1) * 8)))
                    atomicAdd(&hist[(u >> (byt * 8)) & 255], 1);
            }
            __syncthreads();
            if (tid == 0) {
                int cum = 0, B = 0, kept = 0, abnew = above;
                for (int b = 255; b >= 0; --b) {
                    if (above + cum + hist[b] >= KMIN) {
                        B = b; kept = above + cum + hist[b]; abnew = above + cum; break;
                    }
                    cum += hist[b];
                }
                if (kept <= KEEP - 1) { sh_thresh = sh_pref | ((unsigned)B << (byt * 8)); sh_done = 1; }
                else {
                    above = abnew;
                    sh_pref = sh_pref | ((unsigned)B << (byt * 8));
                    if (byt == 0) sh_fail = 1;
                }
            }
            __syncthreads();
            if (sh_done || sh_fail) break;
        }
        if (sh_fail) {
            if (tid == 0) { fullflag[g] = 1; kcount[g] = 0; }
            return;
        }
        thresh = sh_thresh;
    }
    if (tid == 0) sh_cnt = 0;
    __syncthreads();
    for (int c = tid; c < nc; c += 256) {
        unsigned u = f2u(__int_as_float(src[c].y));
        if (u >= thresh) {
            int slot = atomicAdd(&sh_cnt, 1);
            keys[slot] = ((unsigned long long)(~u) << 32) | (unsigned)src[c].x;
        }
    }
    __syncthreads();
    int kept = sh_cnt;
    for (int i = tid; i < KEEP; i += 256) if (i >= kept) keys[i] = ~0ull;
    __syncthreads();
    for (int k = 2; k <= KEEP; k <<= 1) {
        for (int j = k >> 1; j > 0; j >>= 1) {
            for (int i = tid; i < KEEP; i += 256) {
                int ixj = i ^ j;
                if (ixj > i) {
                    unsigned long long a = keys[i], b = keys[ixj];
                    bool up = ((i & k) == 0);
                    if ((up && a > b) || (!up && a < b)) { keys[i] = b; keys[ixj] = a; }
                }
            }
            __syncthreads();
        }
    }
    for (int i = tid; i < KEEP; i += 256) scand[(size_t)g * KEEP + i] = keys[i];
    if (tid == 0) { kcount[g] = kept; fullflag[g] = 0; }
}

// sequential dynamic assignment, single wave: walk each gt's sorted prefix,
// ballot/popcount rank-select first 10 unused; LDS used-bitmap.
__global__ __launch_bounds__(64) void k_dyn2(
    const int* __restrict__ order, const int* __restrict__ kcount,
    const unsigned long long* __restrict__ scand, const int* __restrict__ fullflag,
    const int* __restrict__ ccnt, const int2* __restrict__ cpair,
    const unsigned* __restrict__ usedbits_g, const int* __restrict__ failFlag,
    int* __restrict__ out)
{
    __shared__ unsigned bits[2048];
    int lane = threadIdx.x;
    for (int w = lane; w < 2048; w += 64) bits[w] = usedbits_g[w];
    __syncthreads();
    bool globalFull = (*failFlag != 0);

    for (int k = 0; k < NGT; ++k) {
        int gt = order[k];
        int got = 0;
        if (!globalFull && fullflag[gt] == 0) {
            int kept = kcount[gt];
            int base = 0;
            while (got < 10 && base < kept) {
                int i = base + lane;
                unsigned long long key = (i < kept) ? scand[(size_t)gt * KEEP + i] : ~0ull;
                int p = (int)(unsigned)(key & 0xFFFFFFFFull);
                bool ok = (key != ~0ull) && !((bits[p >> 5] >> (p & 31)) & 1u);
                unsigned long long mask = __ballot(ok);
                int need = 10 - got;
                int pre = __popcll(mask & ((1ull << lane) - 1ull));
                if (ok && pre < need) {
                    out[128 + k * 10 + got + pre] = p;
                    out[1408 + 128 + k * 10 + got + pre] = gt;
                    atomicOr(&bits[p >> 5], 1u << (p & 31));
                }
                int tot = __popcll(mask);
                got += (tot < need) ? tot : need;
                base += 64;
                __syncthreads();
            }
        } else {
            int nc = ccnt[gt]; if (nc > CAP) nc = CAP;
            float lv[10]; int li[10];
#pragma unroll
            for (int q = 0; q < 10; ++q) { lv[q] = -1e30f; li[q] = SENT_I; }
            for (int c = lane; c < nc; c += 64) {
                int2 pr = cpair[(size_t)gt * CAP + c];
                int p = pr.x;
                if ((bits[p >> 5] >> (p & 31)) & 1u) continue;
                float cv = __int_as_float(pr.y); int ci = p;
#pragma unroll
                for (int q = 0; q < 10; ++q) {
                    bool b = (cv > lv[q]) || (cv == lv[q] && ci < li[q]);
                    float tv = b ? lv[q] : cv; int ti = b ? li[q] : ci;
                    if (b) { lv[q] = cv; li[q] = ci; }
                    cv = tv; ci = ti;
                }
            }
#pragma unroll
            for (int q = 0; q < 10; ++q) {
                float mo = lv[0]; int mj = li[0];
#pragma unroll
                for (int off = 1; off < 64; off <<= 1) {
                    float ov = __shfl_xor(mo, off, 64);
                    int oj = __shfl_xor(mj, off, 64);
                    if (ov > mo || (ov == mo && oj < mj)) { mo = ov; mj = oj; }
                }
                bool valid = (mj != SENT_I);
                if (valid && li[0] == mj) {
#pragma unroll
                    for (int t = 0; t < 9; ++t) { lv[t] = lv[t + 1]; li[t] = li[t + 1]; }
                    lv[9] = -1e30f; li[9] = SENT_I;
                }
                if (lane == q) {
                    out[128 + k * 10 + q] = valid ? mj : -1;
                    out[1408 + 128 + k * 10 + q] = valid ? gt : -1;
                    if (valid) atomicOr(&bits[mj >> 5], 1u << (mj & 31));
                }
            }
            got = 10;
            __syncthreads();
        }
        for (int q = got + lane; q < 10; q += 64) {
            out[128 + k * 10 + q] = -1;
            out[1408 + 128 + k * 10 + q] = -1;
        }
        __syncthreads();
    }
}

// ---------- launch ----------

extern "C" void kernel_launch(void* const* d_in, const int* in_sizes, int n_in,
                              void* d_out, int out_size, void* d_ws, size_t ws_size,
                              hipStream_t stream) {
    const float* pc  = (const float*)d_in[0];
    const float* ps  = (const float*)d_in[1];
    const float* cls = (const float*)d_in[2];
    const float* gc  = (const float*)d_in[4];
    const float* gs  = (const float*)d_in[5];
    const int*   lab = (const int*)d_in[6];

    char* ws = (char*)d_ws;
    float*         costT    = (float*)(ws + 0);                  // 33,554,432
    // scand ALIASES costT[0..2MB]: k_prep launched after k_lsa_sparse/k_lsa_dense
    unsigned long long* scand = (unsigned long long*)(ws + 0);   //  2,097,152 (over costT)
    // rowlist ALIASES dense-fallback v (dead before fallback would run)
    int2*          rowlist  = (int2*)(ws + 33554432);            //    135,168 (over v)
    double*        v        = (double*)(ws + 33554432);          //    524,288 (fallback only)
    double*        shortest = (double*)(ws + 34078720);          //    524,288 (fallback only)
    int*           path     = (int*)(ws + 34603008);             //    262,144 (fallback only)
    int*           row4col  = (int*)(ws + 34865152);             //    262,144 (fallback only)
    unsigned char* SC       = (unsigned char*)(ws + 35127296);   //     65,536 (fallback only)
    int*           kcount   = (int*)(ws + 35192832);             //        512
    int*           fullflag = (int*)(ws + 35193344);             //        512
    int*           ccnt     = (int*)(ws + 35193856);             //        512
    unsigned*      cmax     = (unsigned*)(ws + 35194368);        //        512
    int*           order    = (int*)(ws + 35194880);             //        512
    int*           failFlag = (int*)(ws + 35195392);             //        512
    unsigned*      usedbits = (unsigned*)(ws + 35195904);        //      8,192
    int2*          cpair    = (int2*)(ws + 35204096);            // 12,582,912 -> end 47,787,008

    int* out = (int*)d_out;

    hipLaunchKernelGGL(k_init, dim3(1), dim3(128), 0, stream, ccnt, cmax, failFlag);
    hipLaunchKernelGGL(k_gather, dim3(NPRED / 64), dim3(256), 0, stream,
                       cls, lab, costT);
    hipLaunchKernelGGL(k_cost, dim3(NPRED / 256), dim3(256), 0, stream,
                       pc, ps, gc, gs, costT, ccnt, cmax, cpair);
    hipLaunchKernelGGL(k_sort, dim3(1), dim3(128), 0, stream, cmax, order);
    hipLaunchKernelGGL(k_toprow, dim3(NGT), dim3(256), 0, stream, costT, rowlist);
    hipLaunchKernelGGL(k_lsa_sparse, dim3(1), dim3(64), 0, stream,
                       costT, rowlist, failFlag, usedbits, out);
    hipLaunchKernelGGL(k_lsa_dense, dim3(1), dim3(1024), 0, stream,
                       costT, failFlag, v, shortest, path, row4col, SC, usedbits, out);
    hipLaunchKernelGGL(k_prep, dim3(NGT), dim3(256), 0, stream,
                       cpair, ccnt, scand, kcount, fullflag);
    hipLaunchKernelGGL(k_dyn2, dim3(1), dim3(64), 0, stream,
                       order, kcount, scand, fullflag, ccnt, cpair, usedbits, failFlag, out);
}

// Round 9
// 1113.001 us; speedup vs baseline: 1.7262x; 1.7262x over previous
//
#include <hip/hip_runtime.h>
#include <hip/hip_bf16.h>
#include <math.h>

#define NPRED 65536
#define NGT   128
#define NCLS  256
#define CAP   12288
#define VCAP  160
#define NLIST 129    // per-row sorted prefix: 128 (max |V|) + 1 guarantees a fresh head
#define LSTRIDE 132
#define KEEP  2048
#define KMIN  1418
#define GSPLIT 4     // k_cost g-split: 4 blocks of 32 gts per 256-pred slab
#define GPB   (NGT / GSPLIT)
#define SENT_I 0x7FFFFFFF

// ---------- numeric helpers (match reference op order; no FMA contraction) ----------

// monotone map f32 -> uint32 (order-preserving for all floats)
__device__ __forceinline__ unsigned f2u(float f) {
    unsigned u = __float_as_uint(f);
    return (u & 0x80000000u) ? ~u : (u | 0x80000000u);
}
__device__ __forceinline__ float u2f(unsigned x) {
    unsigned u = (x & 0x80000000u) ? (x ^ 0x80000000u) : ~x;
    return __uint_as_float(u);
}

__device__ __forceinline__ float giou3d(
    float pl0, float pl1, float pl2, float ph0, float ph1, float ph2, float pvol,
    float gl0, float gl1, float gl2, float gh0, float gh1, float gh2, float gvol)
{
#pragma clang fp contract(off)
    float c0 = fmaxf(fminf(ph0, gh0) - fmaxf(pl0, gl0), 0.0f);
    float c1 = fmaxf(fminf(ph1, gh1) - fmaxf(pl1, gl1), 0.0f);
    float c2 = fmaxf(fminf(ph2, gh2) - fmaxf(pl2, gl2), 0.0f);
    float overlap = (c0 * c1) * c2;
    float uni = fmaxf((pvol + gvol) - overlap, 1e-6f);
    float iou = overlap / uni;
    float e0 = fmaxf(fmaxf(ph0, gh0) - fminf(pl0, gl0), 0.0f);
    float e1 = fmaxf(fmaxf(ph1, gh1) - fminf(pl1, gl1), 0.0f);
    float e2 = fmaxf(fmaxf(ph2, gh2) - fminf(pl2, gl2), 0.0f);
    float enc = fmaxf((e0 * e1) * e2, 1e-6f);
    return iou - (enc - uni) / enc;
}

// ---------- kernels ----------

__global__ void k_init(int* ccnt, unsigned* cmax, int* failFlag) {
    int t = threadIdx.x;
    if (t < NGT) { ccnt[t] = 0; cmax[t] = 0u; }
    if (t == 0) *failFlag = 0;
}

// coalesced cls load + LDS transpose + sigmoid: costT[g][p] = -sigmoid(cls[p][lab[g]])
__global__ __launch_bounds__(256) void k_gather(
    const float* __restrict__ cls, const int* __restrict__ lab,
    float* __restrict__ costT)
{
#pragma clang fp contract(off)
    __shared__ float tile[64][NCLS + 1];
    __shared__ int labl[NGT];
    int tid = threadIdx.x;
    int p0 = blockIdx.x * 64;
    if (tid < NGT) labl[tid] = lab[tid];
    for (int it = 0; it < 16; ++it) {
        int row = it * 4 + (tid >> 6);
        int col = (tid & 63) * 4;
        const float4 v = *(const float4*)&cls[(size_t)(p0 + row) * NCLS + col];
        tile[row][col + 0] = v.x; tile[row][col + 1] = v.y;
        tile[row][col + 2] = v.z; tile[row][col + 3] = v.w;
    }
    __syncthreads();
    int lane = tid & 63;
    for (int rep = 0; rep < 32; ++rep) {
        int g = rep * 4 + (tid >> 6);
        float val = tile[lane][labl[g]];
        double s = 1.0 / (1.0 + exp(-(double)val));
        costT[(size_t)g * NPRED + p0 + lane] = -(float)s;
    }
}

// two-pass, block-aggregated atomics. Grid: (NPRED/256)*GSPLIT blocks x 256 thr.
// Block handles 256 preds x GPB gts. Pass A: giou + LDS max/count + costT RMW.
// Then 1 parallel global atomicAdd per gt. Pass B: recompute giou, scatter cpair.
__global__ __launch_bounds__(256) void k_cost(
    const float* __restrict__ pc, const float* __restrict__ ps,
    const float* __restrict__ gc, const float* __restrict__ gs,
    float* __restrict__ costT, int* __restrict__ ccnt, unsigned* __restrict__ cmax,
    int2* __restrict__ cpair)
{
#pragma clang fp contract(off)
    __shared__ float gb[GPB][6];
    __shared__ float gvol[GPB];
    __shared__ unsigned smax[GPB];
    __shared__ int cntl[GPB], basel[GPB], curl[GPB];
    int tid = threadIdx.x;
    int lane = tid & 63;
    int g0 = (blockIdx.x & (GSPLIT - 1)) * GPB;
    int p  = (blockIdx.x >> 2) * 256 + tid;

    if (tid < GPB) {
        int g = g0 + tid;
        float c0 = gc[g * 3 + 0], c1 = gc[g * 3 + 1], c2 = gc[g * 3 + 2];
        float s0 = gs[g * 3 + 0], s1 = gs[g * 3 + 1], s2 = gs[g * 3 + 2];
        float l0 = c0 - s0 / 2.0f, l1 = c1 - s1 / 2.0f, l2 = c2 - s2 / 2.0f;
        float h0 = c0 + s0 / 2.0f, h1 = c1 + s1 / 2.0f, h2 = c2 + s2 / 2.0f;
        gb[tid][0] = l0; gb[tid][1] = l1; gb[tid][2] = l2;
        gb[tid][3] = h0; gb[tid][4] = h1; gb[tid][5] = h2;
        gvol[tid] = ((h0 - l0) * (h1 - l1)) * (h2 - l2);
        smax[tid] = 0u; cntl[tid] = 0; curl[tid] = 0;
    }
    __syncthreads();

    float c0 = pc[p * 3 + 0], c1 = pc[p * 3 + 1], c2 = pc[p * 3 + 2];
    float s0 = ps[p * 3 + 0], s1 = ps[p * 3 + 1], s2 = ps[p * 3 + 2];
    float pl0 = c0 - s0 / 2.0f, pl1 = c1 - s1 / 2.0f, pl2 = c2 - s2 / 2.0f;
    float ph0 = c0 + s0 / 2.0f, ph1 = c1 + s1 / 2.0f, ph2 = c2 + s2 / 2.0f;
    float pvol = ((ph0 - pl0) * (ph1 - pl1)) * (ph2 - pl2);

    // Pass A: no blocking global atomics in the loop
    for (int gg = 0; gg < GPB; ++gg) {
        float gio = giou3d(pl0, pl1, pl2, ph0, ph1, ph2, pvol,
                           gb[gg][0], gb[gg][1], gb[gg][2], gb[gg][3], gb[gg][4], gb[gg][5],
                           gvol[gg]);
        float m = gio;
        for (int off = 32; off; off >>= 1) m = fmaxf(m, __shfl_xor(m, off, 64));
        unsigned long long mask = __ballot(gio > 0.25f);
        if (lane == 0) {
            atomicMax(&smax[gg], f2u(m));
            atomicAdd(&cntl[gg], __popcll(mask));
        }
        size_t ij = (size_t)(g0 + gg) * NPRED + p;
        float ns = costT[ij];                 // staged -sigmoid
        costT[ij] = ns + (2.0f * (-gio));     // == (-sg) + (2.0f*(-gio))
    }
    __syncthreads();
    // one parallel global atomic per gt (32 concurrent RTs); cmax fire-and-forget
    if (tid < GPB) {
        atomicMax(&cmax[g0 + tid], smax[tid]);
        basel[tid] = atomicAdd(&ccnt[g0 + tid], cntl[tid]);
    }
    __syncthreads();

    // Pass B: recompute giou (deterministic), scatter candidates
    for (int gg = 0; gg < GPB; ++gg) {
        float gio = giou3d(pl0, pl1, pl2, ph0, ph1, ph2, pvol,
                           gb[gg][0], gb[gg][1], gb[gg][2], gb[gg][3], gb[gg][4], gb[gg][5],
                           gvol[gg]);
        bool cand = (gio > 0.25f);
        unsigned long long mask = __ballot(cand);
        int cnt = __popcll(mask);
        int wo = 0;
        if (lane == 0 && cnt) wo = atomicAdd(&curl[gg], cnt);
        wo = __shfl(wo, 0, 64);
        if (cand) {
            int slot = basel[gg] + wo + __popcll(mask & ((1ull << lane) - 1ull));
            if (slot < CAP)
                cpair[(size_t)(g0 + gg) * CAP + slot] = make_int2(p, __float_as_int(gio));
        }
    }
}

__global__ __launch_bounds__(128) void k_sort(const unsigned* __restrict__ cmax,
                                              int* __restrict__ order) {
    __shared__ unsigned m[NGT];
    int t = threadIdx.x;
    m[t] = cmax[t];
    __syncthreads();
    unsigned mt = m[t];
    int r = 0;
    for (int k = 0; k < NGT; ++k) {
        unsigned mk = m[k];
        if (mk < mt || (mk == mt && k < t)) r++;
    }
    order[r] = t;
}

// per-row exact top-NLIST smallest (value, col) via 8-pass u64 radix-select
__global__ __launch_bounds__(256) void k_toprow(
    const float* __restrict__ costT, int2* __restrict__ rowlist)
{
    __shared__ int hist[256];
    __shared__ unsigned long long keys[256];
    __shared__ unsigned long long sh_prefix;
    __shared__ int sh_rank, sh_cnt;
    int tid = threadIdx.x;
    int row = blockIdx.x;
    const float* crow = costT + (size_t)row * NPRED;
    if (tid == 0) { sh_prefix = 0ull; sh_rank = NLIST - 1; sh_cnt = 0; }
    __syncthreads();
    for (int d = 7; d >= 0; --d) {
        hist[tid] = 0;
        __syncthreads();
        unsigned long long pref = sh_prefix;
        int sh = (d + 1) * 8;
        for (int j = tid; j < NPRED; j += 256) {
            unsigned long long key = ((unsigned long long)f2u(crow[j]) << 32) | (unsigned)j;
            bool match = (sh >= 64) || ((key >> sh) == (pref >> sh));
            if (match) atomicAdd(&hist[(int)((key >> (d * 8)) & 255ull)], 1);
        }
        __syncthreads();
        if (tid == 0) {
            int rank = sh_rank, cum = 0, b = 0;
            for (; b < 256; ++b) { if (cum + hist[b] > rank) break; cum += hist[b]; }
            sh_prefix = pref | ((unsigned long long)b << (d * 8));
            sh_rank = rank - cum;
        }
        __syncthreads();
    }
    unsigned long long thr = sh_prefix;  // exact NLIST-th smallest key
    for (int j = tid; j < NPRED; j += 256) {
        unsigned long long key = ((unsigned long long)f2u(crow[j]) << 32) | (unsigned)j;
        if (key <= thr) { int s = atomicAdd(&sh_cnt, 1); keys[s] = key; }
    }
    __syncthreads();
    if (tid >= sh_cnt) keys[tid] = ~0ull;
    __syncthreads();
    for (int k = 2; k <= 256; k <<= 1) {
        for (int j2 = k >> 1; j2 > 0; j2 >>= 1) {
            int i = tid, ixj = i ^ j2;
            if (ixj > i) {
                unsigned long long a = keys[i], b2 = keys[ixj];
                bool up = ((i & k) == 0);
                if ((up && a > b2) || (!up && a < b2)) { keys[i] = b2; keys[ixj] = a; }
            }
            __syncthreads();
        }
    }
    if (tid < NLIST) {
        unsigned long long key = keys[tid];
        rowlist[row * LSTRIDE + tid] =
            make_int2(__float_as_int(u2f((unsigned)(key >> 32))),
                      (int)(unsigned)(key & 0xFFFFFFFFull));
    }
}

// sparse JV LSA, single wave. Fresh-column heads from per-row sorted top-NLIST
// lists. Bit-identical to dense numpy JV (exact f64 op order, lex tie-breaks).
__global__ __launch_bounds__(64) void k_lsa_sparse(
    const float* __restrict__ costT, const int2* __restrict__ rowlist,
    int* __restrict__ failFlag,
    unsigned* __restrict__ usedbits, int* __restrict__ out)
{
#pragma clang fp contract(off)
    __shared__ double u_l[NGT];
    __shared__ int    c4r[NGT];
    __shared__ int    slot4row[NGT];
    __shared__ int    headpos[NGT];
    __shared__ int    colidV[VCAP];
    __shared__ double vV[VCAP], shortV[VCAP];
    __shared__ int    pathV[VCAP], r4cV[VCAP];
    __shared__ unsigned char SCV[VCAP];
    __shared__ int    SRr[VCAP];
    __shared__ double headv[VCAP];
    __shared__ int    headj[VCAP];
    __shared__ unsigned vbits[2048];
    __shared__ int S_bi, S_sink, S_nSR, S_nV, S_fail, S_pendrow, S_pendpos;
    __shared__ double S_mv, S_pendmv;

    int lane = threadIdx.x;
    for (int w = lane; w < 2048; w += 64) vbits[w] = 0u;
    for (int r = lane; r < NGT; r += 64) {
        u_l[r] = 0.0; c4r[r] = -1; slot4row[r] = -1; headpos[r] = 0;
    }
    if (lane == 0) { S_nV = 0; S_fail = 0; }
    __syncthreads();

    for (int cur = 0; cur < NGT; ++cur) {
        int nV0 = S_nV;
        for (int k = lane; k < nV0; k += 64) { shortV[k] = INFINITY; pathV[k] = -1; SCV[k] = 0; }
        if (lane == 0) {
            S_bi = cur; S_sink = -1; S_mv = 0.0;
            SRr[0] = cur; S_nSR = 1;
            S_pendrow = cur; S_pendpos = 0; S_pendmv = 0.0;
        }
        __syncthreads();

        while (true) {
            int prow = S_pendrow;
            if (prow >= 0) {
                int pos = headpos[prow];
                float hval = 0.0f; int hcol = SENT_I;
                while (pos < NLIST) {
                    int i = pos + lane;
                    int2 e = (i < NLIST) ? rowlist[prow * LSTRIDE + i] : make_int2(0, SENT_I);
                    int c = e.y;
                    bool fresh = (i < NLIST) && !((vbits[c >> 5] >> (c & 31)) & 1u);
                    unsigned long long m = __ballot(fresh);
                    if (m) {
                        int fl = __ffsll(m) - 1;
                        hcol = __shfl(c, fl, 64);
                        hval = __shfl(__int_as_float(e.x), fl, 64);
                        pos += fl;
                        break;
                    }
                    pos += 64;
                }
                if (lane == 0) {
                    headpos[prow] = pos;
                    int pp = S_pendpos;
                    headj[pp] = hcol;
                    headv[pp] = (hcol == SENT_I) ? (double)INFINITY
                                                 : ((S_pendmv + (double)hval) - u_l[prow]);
                    S_pendrow = -1;
                }
                __syncthreads();
            }

            int bi = S_bi; double mv = S_mv; int nV = S_nV; int s = S_nSR;
            double ui = u_l[bi];
            double bv = (double)INFINITY; int bj = SENT_I, bp = SENT_I, baux = -1, bisv = 0;
            for (int k = lane; k < nV; k += 64) {
                if (!SCV[k]) {
                    double c = (double)costT[(size_t)bi * NPRED + colidV[k]];
                    double r = ((mv + c) - ui) - vV[k];
                    if (r < shortV[k]) { shortV[k] = r; pathV[k] = bi; }
                    double sval = shortV[k]; int scol = colidV[k];
                    if (sval < bv || (sval == bv && scol < bj)) {
                        bv = sval; bj = scol; bp = SENT_I; baux = k; bisv = 1;
                    }
                }
            }
            for (int p = lane; p < s; p += 64) {
                double hv = headv[p]; int hj = headj[p];
                if (hv < bv || (hv == bv && (hj < bj || (hj == bj && p < bp)))) {
                    bv = hv; bj = hj; bp = p; baux = p; bisv = 0;
                }
            }
            for (int off = 1; off < 64; off <<= 1) {
                double ov = __shfl_xor(bv, off, 64);
                int oj = __shfl_xor(bj, off, 64);
                int op = __shfl_xor(bp, off, 64);
                int oa = __shfl_xor(baux, off, 64);
                int oi = __shfl_xor(bisv, off, 64);
                if (ov < bv || (ov == bv && (oj < bj || (oj == bj && op < bp)))) {
                    bv = ov; bj = oj; bp = op; baux = oa; bisv = oi;
                }
            }
            if (lane == 0) {
                S_mv = bv;
                if (bisv) {
                    SCV[baux] = 1;
                    int nr = r4cV[baux];
                    SRr[s] = nr;
                    headv[s] = (double)INFINITY; headj[s] = SENT_I;
                    S_pendrow = nr; S_pendpos = s; S_pendmv = bv;
                    S_nSR = s + 1; S_bi = nr;
                } else {
                    int k2 = S_nV;
                    if (k2 >= VCAP) S_fail = 1;
                    else {
                        colidV[k2] = bj; vV[k2] = 0.0; shortV[k2] = bv;
                        pathV[k2] = SRr[baux]; SCV[k2] = 1; r4cV[k2] = -1;
                        vbits[bj >> 5] |= (1u << (bj & 31));
                        S_nV = k2 + 1;
                        S_sink = bj;
                    }
                }
            }
            __syncthreads();
            if (S_sink >= 0 || S_fail) break;
        }
        if (S_fail) break;

        double mvf = S_mv;
        int nVn = S_nV;
        for (int k = lane; k < nVn; k += 64)
            if (SCV[k]) vV[k] -= (mvf - shortV[k]);
        if (lane == 0) {
            u_l[cur] += mvf;
            int s = S_nSR;
            for (int q = 1; q < s; ++q) {
                int i2 = SRr[q];
                u_l[i2] += mvf - shortV[slot4row[i2]];
            }
            int jslot = S_nV - 1;
            while (true) {
                int i2 = pathV[jslot];
                r4cV[jslot] = i2;
                int oldslot = (c4r[i2] >= 0) ? slot4row[i2] : -1;
                c4r[i2] = colidV[jslot];
                slot4row[i2] = jslot;
                if (i2 == cur) break;
                jslot = oldslot;
            }
        }
        __syncthreads();
    }

    if (lane == 0 && S_fail) *failFlag = 1;
    __syncthreads();
    if (!S_fail) {
        for (int w = lane; w < 2048; w += 64) usedbits[w] = 0u;
        __syncthreads();
        for (int r = lane; r < NGT; r += 64) {
            int p = c4r[r];
            atomicOr(&usedbits[p >> 5], 1u << (p & 31));
            out[r] = p;
            out[1408 + r] = r;
        }
    }
}

// dense fallback: only runs if k_lsa_sparse flagged overflow (should never happen)
__global__ __launch_bounds__(1024) void k_lsa_dense(
    const float* __restrict__ costT, const int* __restrict__ failFlag,
    double* __restrict__ v, double* __restrict__ shortest,
    int* __restrict__ path, int* __restrict__ row4col,
    unsigned char* __restrict__ SC, unsigned* __restrict__ usedbits,
    int* __restrict__ out)
{
#pragma clang fp contract(off)
    if (*failFlag == 0) return;
    __shared__ double u_l[NGT];
    __shared__ int    c4r[NGT];
    __shared__ int    SR[NGT + 1];
    __shared__ int    bi, bsink, nSR;
    __shared__ double bmin;
    __shared__ double wval[16];
    __shared__ int    widx[16];
    int tid = threadIdx.x;

    for (int j = tid; j < NPRED; j += 1024) { v[j] = 0.0; row4col[j] = -1; }
    if (tid < NGT) { u_l[tid] = 0.0; c4r[tid] = -1; }
    __syncthreads();

    for (int cur = 0; cur < NGT; ++cur) {
        for (int j = tid; j < NPRED; j += 1024) {
            shortest[j] = (double)INFINITY; path[j] = -1; SC[j] = 0;
        }
        if (tid == 0) { bi = cur; bsink = -1; bmin = 0.0; SR[0] = cur; nSR = 1; }
        __syncthreads();

        while (true) {
            int irow = bi;
            double mv = bmin;
            double ui = u_l[irow];
            const float* crow = costT + (size_t)irow * NPRED;
            double bestv = (double)INFINITY;
            int    bestj = SENT_I;
            for (int j = tid; j < NPRED; j += 1024) {
                if (!SC[j]) {
                    double s = shortest[j];
                    double r = ((mv + (double)crow[j]) - ui) - v[j];
                    if (r < s) { s = r; shortest[j] = r; path[j] = irow; }
                    if (s < bestv || (s == bestv && j < bestj)) { bestv = s; bestj = j; }
                }
            }
            for (int off = 32; off; off >>= 1) {
                double ov = __shfl_down(bestv, off, 64);
                int    oj = __shfl_down(bestj, off, 64);
                if (ov < bestv || (ov == bestv && oj < bestj)) { bestv = ov; bestj = oj; }
            }
            if ((tid & 63) == 0) { wval[tid >> 6] = bestv; widx[tid >> 6] = bestj; }
            __syncthreads();
            if (tid == 0) {
                double bv = wval[0]; int bj = widx[0];
                for (int w = 1; w < 16; ++w) {
                    double ov = wval[w]; int oj = widx[w];
                    if (ov < bv || (ov == bv && oj < bj)) { bv = ov; bj = oj; }
                }
                bmin = bv;
                SC[bj] = 1;
                int r = row4col[bj];
                if (r < 0) { bsink = bj; }
                else       { SR[nSR++] = r; bi = r; }
            }
            __syncthreads();
            if (bsink >= 0) break;
        }

        double mv = bmin;
        for (int j = tid; j < NPRED; j += 1024)
            if (SC[j]) v[j] -= (mv - shortest[j]);
        if (tid == 0) {
            u_l[cur] += mv;
            for (int k = 1; k < nSR; ++k) {
                int i2 = SR[k];
                u_l[i2] += mv - shortest[c4r[i2]];
            }
            int j = bsink;
            while (true) {
                int i2 = path[j];
                row4col[j] = i2;
                int nj = c4r[i2];
                c4r[i2] = j;
                j = nj;
                if (i2 == cur) break;
            }
        }
        __syncthreads();
    }

    for (int w = tid; w < 2048; w += 1024) usedbits[w] = 0u;
    __syncthreads();
    for (int j = tid; j < NPRED; j += 1024)
        if (row4col[j] >= 0) atomicOr(&usedbits[j >> 5], 1u << (j & 31));
    if (tid < NGT) {
        out[tid]        = c4r[tid];
        out[1408 + tid] = tid;
    }
}

// per-gt: histogram-select top >=KMIN by (val desc, idx asc), compact <=KEEP-1,
// bitonic-sort KEEP u64 keys in LDS, write sorted prefix.
__global__ __launch_bounds__(256) void k_prep(
    const int2* __restrict__ cpair, const int* __restrict__ ccnt,
    unsigned long long* __restrict__ scand, int* __restrict__ kcount,
    int* __restrict__ fullflag)
{
    __shared__ int hist[256];
    __shared__ unsigned long long keys[KEEP];
    __shared__ unsigned sh_pref, sh_thresh;
    __shared__ int sh_done, sh_fail, sh_cnt;
    int tid = threadIdx.x;
    int g = blockIdx.x;
    int nc = ccnt[g]; if (nc > CAP) nc = CAP;
    const int2* src = cpair + (size_t)g * CAP;

    unsigned thresh = 0;
    if (nc > KEEP - 1) {
        if (tid == 0) { sh_pref = 0; sh_done = 0; sh_fail = 0; }
        __syncthreads();
        int above = 0;
        for (int byt = 3; byt >= 0; --byt) {
            hist[tid] = 0;
            __syncthreads();
            unsigned pref = sh_pref;
            for (int c = tid; c < nc; c += 256) {
                unsigned u = f2u(__int_as_float(src[c].y));
                if (byt == 3 || (u >> ((byt + 1) * 8)) == (pref >> ((byt + 1) * 8)))
                    atomicAdd(&hist[(u >> (byt * 8)) & 255], 1);
            }
            __syncthreads();
            if (tid == 0) {
                int cum = 0, B = 0, kept = 0, abnew = above;
                for (int b = 255; b >= 0; --b) {
                    if (above + cum + hist[b] >= KMIN) {
                        B = b; kept = above + cum + hist[b]; abnew = above + cum; break;
                    }
                    cum += hist[b];
                }
                if (kept <= KEEP - 1) { sh_thresh = sh_pref | ((unsigned)B << (byt * 8)); sh_done = 1; }
                else {
                    above = abnew;
                    sh_pref = sh_pref | ((unsigned)B << (byt * 8));
                    if (byt == 0) sh_fail = 1;
                }
            }
            __syncthreads();
            if (sh_done || sh_fail) break;
        }
        if (sh_fail) {
            if (tid == 0) { fullflag[g] = 1; kcount[g] = 0; }
            return;
        }
        thresh = sh_thresh;
    }
    if (tid == 0) sh_cnt = 0;
    __syncthreads();
    for (int c = tid; c < nc; c += 256) {
        unsigned u = f2u(__int_as_float(src[c].y));
        if (u >= thresh) {
            int slot = atomicAdd(&sh_cnt, 1);
            keys[slot] = ((unsigned long long)(~u) << 32) | (unsigned)src[c].x;
        }
    }
    __syncthreads();
    int kept = sh_cnt;
    for (int i = tid; i < KEEP; i += 256) if (i >= kept) keys[i] = ~0ull;
    __syncthreads();
    for (int k = 2; k <= KEEP; k <<= 1) {
        for (int j = k >> 1; j > 0; j >>= 1) {
            for (int i = tid; i < KEEP; i += 256) {
                int ixj = i ^ j;
                if (ixj > i) {
                    unsigned long long a = keys[i], b = keys[ixj];
                    bool up = ((i & k) == 0);
                    if ((up && a > b) || (!up && a < b)) { keys[i] = b; keys[ixj] = a; }
                }
            }
            __syncthreads();
        }
    }
    for (int i = tid; i < KEEP; i += 256) scand[(size_t)g * KEEP + i] = keys[i];
    if (tid == 0) { kcount[g] = kept; fullflag[g] = 0; }
}

// sequential dynamic assignment, single wave
__global__ __launch_bounds__(64) void k_dyn2(
    const int* __restrict__ order, const int* __restrict__ kcount,
    const unsigned long long* __restrict__ scand, const int* __restrict__ fullflag,
    const int* __restrict__ ccnt, const int2* __restrict__ cpair,
    const unsigned* __restrict__ usedbits_g, const int* __restrict__ failFlag,
    int* __restrict__ out)
{
    __shared__ unsigned bits[2048];
    int lane = threadIdx.x;
    for (int w = lane; w < 2048; w += 64) bits[w] = usedbits_g[w];
    __syncthreads();
    bool globalFull = (*failFlag != 0);

    for (int k = 0; k < NGT; ++k) {
        int gt = order[k];
        int got = 0;
        if (!globalFull && fullflag[gt] == 0) {
            int kept = kcount[gt];
            int base = 0;
            while (got < 10 && base < kept) {
                int i = base + lane;
                unsigned long long key = (i < kept) ? scand[(size_t)gt * KEEP + i] : ~0ull;
                int p = (int)(unsigned)(key & 0xFFFFFFFFull);
                bool ok = (key != ~0ull) && !((bits[p >> 5] >> (p & 31)) & 1u);
                unsigned long long mask = __ballot(ok);
                int need = 10 - got;
                int pre = __popcll(mask & ((1ull << lane) - 1ull));
                if (ok && pre < need) {
                    out[128 + k * 10 + got + pre] = p;
                    out[1408 + 128 + k * 10 + got + pre] = gt;
                    atomicOr(&bits[p >> 5], 1u << (p & 31));
                }
                int tot = __popcll(mask);
                got += (tot < need) ? tot : need;
                base += 64;
                __syncthreads();
            }
        } else {
            int nc = ccnt[gt]; if (nc > CAP) nc = CAP;
            float lv[10]; int li[10];
#pragma unroll
            for (int q = 0; q < 10; ++q) { lv[q] = -1e30f; li[q] = SENT_I; }
            for (int c = lane; c < nc; c += 64) {
                int2 pr = cpair[(size_t)gt * CAP + c];
                int p = pr.x;
                if ((bits[p >> 5] >> (p & 31)) & 1u) continue;
                float cv = __int_as_float(pr.y); int ci = p;
#pragma unroll
                for (int q = 0; q < 10; ++q) {
                    bool b = (cv > lv[q]) || (cv == lv[q] && ci < li[q]);
                    float tv = b ? lv[q] : cv; int ti = b ? li[q] : ci;
                    if (b) { lv[q] = cv; li[q] = ci; }
                    cv = tv; ci = ti;
                }
            }
#pragma unroll
            for (int q = 0; q < 10; ++q) {
                float mo = lv[0]; int mj = li[0];
#pragma unroll
                for (int off = 1; off < 64; off <<= 1) {
                    float ov = __shfl_xor(mo, off, 64);
                    int oj = __shfl_xor(mj, off, 64);
                    if (ov > mo || (ov == mo && oj < mj)) { mo = ov; mj = oj; }
                }
                bool valid = (mj != SENT_I);
                if (valid && li[0] == mj) {
#pragma unroll
                    for (int t = 0; t < 9; ++t) { lv[t] = lv[t + 1]; li[t] = li[t + 1]; }
                    lv[9] = -1e30f; li[9] = SENT_I;
                }
                if (lane == q) {
                    out[128 + k * 10 + q] = valid ? mj : -1;
                    out[1408 + 128 + k * 10 + q] = valid ? gt : -1;
                    if (valid) atomicOr(&bits[mj >> 5], 1u << (mj & 31));
                }
            }
            got = 10;
            __syncthreads();
        }
        for (int q = got + lane; q < 10; q += 64) {
            out[128 + k * 10 + q] = -1;
            out[1408 + 128 + k * 10 + q] = -1;
        }
        __syncthreads();
    }
}

// ---------- launch ----------

extern "C" void kernel_launch(void* const* d_in, const int* in_sizes, int n_in,
                              void* d_out, int out_size, void* d_ws, size_t ws_size,
                              hipStream_t stream) {
    const float* pc  = (const float*)d_in[0];
    const float* ps  = (const float*)d_in[1];
    const float* cls = (const float*)d_in[2];
    const float* gc  = (const float*)d_in[4];
    const float* gs  = (const float*)d_in[5];
    const int*   lab = (const int*)d_in[6];

    char* ws = (char*)d_ws;
    float*         costT    = (float*)(ws + 0);                  // 33,554,432
    unsigned long long* scand = (unsigned long long*)(ws + 0);   //  2,097,152 (over costT; k_prep runs after LSA)
    int2*          rowlist  = (int2*)(ws + 33554432);            //    135,168 (over v)
    double*        v        = (double*)(ws + 33554432);          //    524,288 (fallback only)
    double*        shortest = (double*)(ws + 34078720);          //    524,288 (fallback only)
    int*           path     = (int*)(ws + 34603008);             //    262,144 (fallback only)
    int*           row4col  = (int*)(ws + 34865152);             //    262,144 (fallback only)
    unsigned char* SC       = (unsigned char*)(ws + 35127296);   //     65,536 (fallback only)
    int*           kcount   = (int*)(ws + 35192832);
    int*           fullflag = (int*)(ws + 35193344);
    int*           ccnt     = (int*)(ws + 35193856);
    unsigned*      cmax     = (unsigned*)(ws + 35194368);
    int*           order    = (int*)(ws + 35194880);
    int*           failFlag = (int*)(ws + 35195392);
    unsigned*      usedbits = (unsigned*)(ws + 35195904);        //      8,192
    int2*          cpair    = (int2*)(ws + 35204096);            // 12,582,912 -> end 47,787,008

    int* out = (int*)d_out;

    hipLaunchKernelGGL(k_init, dim3(1), dim3(128), 0, stream, ccnt, cmax, failFlag);
    hipLaunchKernelGGL(k_gather, dim3(NPRED / 64), dim3(256), 0, stream,
                       cls, lab, costT);
    hipLaunchKernelGGL(k_cost, dim3((NPRED / 256) * GSPLIT), dim3(256), 0, stream,
                       pc, ps, gc, gs, costT, ccnt, cmax, cpair);
    hipLaunchKernelGGL(k_sort, dim3(1), dim3(128), 0, stream, cmax, order);
    hipLaunchKernelGGL(k_toprow, dim3(NGT), dim3(256), 0, stream, costT, rowlist);
    hipLaunchKernelGGL(k_lsa_sparse, dim3(1), dim3(64), 0, stream,
                       costT, rowlist, failFlag, usedbits, out);
    hipLaunchKernelGGL(k_lsa_dense, dim3(1), dim3(1024), 0, stream,
                       costT, failFlag, v, shortest, path, row4col, SC, usedbits, out);
    hipLaunchKernelGGL(k_prep, dim3(NGT), dim3(256), 0, stream,
                       cpair, ccnt, scand, kcount, fullflag);
    hipLaunchKernelGGL(k_dyn2, dim3(1), dim3(64), 0, stream,
                       order, kcount, scand, fullflag, ccnt, cpair, usedbits, failFlag, out);
}